// Round 11
// baseline (350.004 us; speedup 1.0000x reference)
//
#include <hip/hip_runtime.h>
#include <hip/hip_fp16.h>

// OTK (optimal-transport kernel attention) for MI355X.
// Pipeline:
//   k0: xT[b][d][n] = fp16(x)            (transpose for k3 B-operand)
//   k1: E[b][h][n][m] = exp(-10*C*pf)    (fp16 MFMA GEMM + fused epilogue)
//   k2: exp-domain Sinkhorn, E streamed from L2 ONCE per iteration
//       (fused row-chunked u+v pass) under waves_per_eu(2,2)
//   k3: out[b][m*4+h][d] = Pt @ x        (fp16 MFMA GEMM)
// Identity: lse_m(K+u+v) = u + lse_m(K+v)  =>  plain Sinkhorn on E=exp(K).
//
// k2 final model (r1-r10): kernel is L2-per-CU bound at ~190 GB/s. r3/r10
// (80us) read E TWICE per iter (remat splits u/v uses). r9's fused body
// reads E once but overflowed the default 64-reg occupancy-target budget
// -> scratch (VALUBusy 4%). r10 proved amdgpu_waves_per_eu(2,2) is
// processed (SGPR 32->112) and raises the budget to 512/2=256. THIS round
// composes the two: fused single-read body (halves L2 bytes) + the
// attribute (fits the ~110-reg transient pressure in registers). Grid runs
// at exactly 2 waves/SIMD anyway, so max=2 costs no real occupancy.

typedef _Float16 h2 __attribute__((ext_vector_type(2)));
typedef _Float16 h8 __attribute__((ext_vector_type(8)));
typedef float f4 __attribute__((ext_vector_type(4)));

#define NB 16
#define NN 2048
#define ND 512
#define NH 4
#define NM 64
#define NITER 30
#define EUSCALE 8.0f   // keeps fp16(eu*EUSCALE) in normal range (eu >= ~1e-5)

static __device__ __forceinline__ float fdot2f(h2 a, h2 b, float c) {
#if __has_builtin(__builtin_amdgcn_fdot2)
  return __builtin_amdgcn_fdot2(a, b, c, false);
#else
  return (float)a[0] * (float)b[0] + (float)a[1] * (float)b[1] + c;
#endif
}

static __device__ __forceinline__ h2 pkrtz(float a, float b) {
  return __builtin_bit_cast(h2, __builtin_amdgcn_cvt_pkrtz(a, b));
}

static __device__ __forceinline__ h8 pack8(float4 a, float4 b) {
  h8 r;
  r[0] = (_Float16)a.x; r[1] = (_Float16)a.y; r[2] = (_Float16)a.z; r[3] = (_Float16)a.w;
  r[4] = (_Float16)b.x; r[5] = (_Float16)b.y; r[6] = (_Float16)b.z; r[7] = (_Float16)b.w;
  return r;
}

static __device__ __forceinline__ float sq4(float4 a) {
  return a.x * a.x + a.y * a.y + a.z * a.z + a.w * a.w;
}

// ---------------------------------------------------------------- k0: x -> xT
__global__ __launch_bounds__(256) void k0_xt(const float* __restrict__ x,
                                             _Float16* __restrict__ xT) {
  __shared__ float tile[64][65];
  const int b = blockIdx.z;
  const int n0 = blockIdx.x * 64;
  const int d0 = blockIdx.y * 64;
  const int t = threadIdx.x;
  const int nr = t >> 2;
  const int ds = (t & 3) * 16;
  const float4* src = (const float4*)(x + ((size_t)(b * NN + n0 + nr) * ND + d0 + ds));
  float4 v0 = src[0], v1 = src[1], v2 = src[2], v3 = src[3];
  float vals[16] = {v0.x, v0.y, v0.z, v0.w, v1.x, v1.y, v1.z, v1.w,
                    v2.x, v2.y, v2.z, v2.w, v3.x, v3.y, v3.z, v3.w};
#pragma unroll
  for (int j = 0; j < 16; ++j) tile[ds + j][nr] = vals[j];
  __syncthreads();
  const int dr = t >> 2;
  const int ns = (t & 3) * 16;
  h8 o0, o1;
#pragma unroll
  for (int j = 0; j < 8; ++j) o0[j] = (_Float16)tile[dr][ns + j];
#pragma unroll
  for (int j = 0; j < 8; ++j) o1[j] = (_Float16)tile[dr][ns + 8 + j];
  _Float16* dst = xT + ((size_t)(b * ND + d0 + dr) * NN + n0 + ns);
  *(h8*)dst = o0;
  *(h8*)(dst + 8) = o1;
}

// ------------------------------------------------------------- k1: build E
__global__ __launch_bounds__(512) void k1_buildE(const float* __restrict__ x,
                                                 const float* __restrict__ w,
                                                 _Float16* __restrict__ E) {
  __shared__ _Float16 Ah[128][72];
  __shared__ _Float16 Bh[256][72];
  __shared__ float x2s[128][4];
  __shared__ float w2s[256][2];
  __shared__ float x2r[128];
  __shared__ float w2r[256];

  const int b = blockIdx.y;
  const int n0 = blockIdx.x * 128;
  const int tid = threadIdx.x;
  const int lane = tid & 63;
  const int wv = tid >> 6;
  const int lrow = lane & 15;
  const int kq = lane >> 4;

  f4 acc[16];
#pragma unroll
  for (int i = 0; i < 16; ++i) acc[i] = (f4){0.f, 0.f, 0.f, 0.f};

  const int ar = tid >> 2, ac = (tid & 3) * 16;
  const int br = tid >> 1, bc = (tid & 1) * 32;
  const float* xsrc = x + ((size_t)(b * NN + n0 + ar) * ND + ac);
  const float* wsrc = w + ((size_t)br * ND + bc);
  float x2p = 0.f, w2p = 0.f;

  for (int kt = 0; kt < 8; ++kt) {
    {
      const float4* s4 = (const float4*)(xsrc + kt * 64);
      float4 a0 = s4[0], a1 = s4[1], a2 = s4[2], a3 = s4[3];
      x2p += sq4(a0) + sq4(a1) + sq4(a2) + sq4(a3);
      *(h8*)&Ah[ar][ac] = pack8(a0, a1);
      *(h8*)&Ah[ar][ac + 8] = pack8(a2, a3);
    }
    {
      const float4* s4 = (const float4*)(wsrc + kt * 64);
      float4 u0 = s4[0], u1 = s4[1], u2 = s4[2], u3 = s4[3];
      float4 u4 = s4[4], u5 = s4[5], u6 = s4[6], u7 = s4[7];
      w2p += sq4(u0) + sq4(u1) + sq4(u2) + sq4(u3)
           + sq4(u4) + sq4(u5) + sq4(u6) + sq4(u7);
      *(h8*)&Bh[br][bc] = pack8(u0, u1);
      *(h8*)&Bh[br][bc + 8] = pack8(u2, u3);
      *(h8*)&Bh[br][bc + 16] = pack8(u4, u5);
      *(h8*)&Bh[br][bc + 24] = pack8(u6, u7);
    }
    __syncthreads();
#pragma unroll
    for (int s = 0; s < 2; ++s) {
      h8 af = *(const h8*)&Ah[wv * 16 + lrow][s * 32 + kq * 8];
#pragma unroll
      for (int cf = 0; cf < 16; ++cf) {
        h8 bf = *(const h8*)&Bh[cf * 16 + lrow][s * 32 + kq * 8];
        acc[cf] = __builtin_amdgcn_mfma_f32_16x16x32_f16(af, bf, acc[cf], 0, 0, 0);
      }
    }
    __syncthreads();
  }

  x2s[ar][tid & 3] = x2p;
  w2s[br][tid & 1] = w2p;
  __syncthreads();
  if (tid < 128) {
    x2r[tid] = x2s[tid][0] + x2s[tid][1] + x2s[tid][2] + x2s[tid][3];
  } else if (tid < 384) {
    const int r = tid - 128;
    w2r[r] = w2s[r][0] + w2s[r][1];
  }
  __syncthreads();

#pragma unroll
  for (int cf = 0; cf < 16; ++cf) {
    const int mg = cf * 16 + lrow;
    const int hh = mg >> 6;
    const int m = mg & 63;
    const float w2v = w2r[mg];
    const float bm = (float)m * (1.0f / 64.0f);
    _Float16* Eb = E + ((size_t)(b * NH + hh) * NN) * NM;
#pragma unroll
    for (int j = 0; j < 4; ++j) {
      const int nl = wv * 16 + kq * 4 + j;
      const int n = n0 + nl;
      const float c2 = x2r[nl] + w2v - 2.0f * acc[cf][j];
      const float Cd = sqrtf(fmaxf(c2, 0.0f));
      const float tt = (float)n * (1.0f / 2048.0f) - bm;
      const float pf = __expf(-100.0f * tt * tt);
      const float Ev = __expf(-10.0f * Cd * pf);
      Eb[(size_t)n * NM + m] = (_Float16)Ev;
    }
  }
}

// ------------------------------------------------------------ k2: Sinkhorn
// One block per (b,h). 512 threads x 4 adjacent rows, FUSED row-chunked
// passes: per row, load once (8 dwordx4), u-dot, eu update, tp accumulate,
// row dies. E read ONCE per iter. waves_per_eu(2,2) raises the RA budget
// to 256 so the ~110-reg transient fits (removes r9's scratch failure).
__global__ __launch_bounds__(512)
__attribute__((amdgpu_waves_per_eu(2, 2)))
void k2_sinkhorn(const _Float16* __restrict__ E,
                 _Float16* __restrict__ Pt) {
  const int bh = blockIdx.x;
  const int b = bh >> 2, h = bh & 3;
  const int tid = threadIdx.x;
  const int lane = tid & 63;

  __shared__ float evf[64];
  __shared__ __align__(16) h2 evh[32];
  __shared__ unsigned int pbuf[512];

  const _Float16* Ep = E + (size_t)bh * (NN * NM);

  float eu[4] = {1.f, 1.f, 1.f, 1.f};
  if (tid < 64) evf[tid] = 1.f;
  if (tid < 32) evh[tid] = pkrtz(1.f, 1.f);
  __syncthreads();

#pragma unroll 1
  for (int it = 0; it < NITER; ++it) {
    asm volatile("" ::: "memory");   // keep E loads inside the loop
    // ev broadcast from LDS (packed fp16)
    h2 evr[32];
    {
      const uint4* ev4 = (const uint4*)evh;
#pragma unroll
      for (int j = 0; j < 8; ++j) {
        uint4 v = ev4[j];
        evr[j * 4 + 0] = __builtin_bit_cast(h2, v.x);
        evr[j * 4 + 1] = __builtin_bit_cast(h2, v.y);
        evr[j * 4 + 2] = __builtin_bit_cast(h2, v.z);
        evr[j * 4 + 3] = __builtin_bit_cast(h2, v.w);
      }
    }
    h2 tp[32];
#pragma unroll
    for (int q = 0; q < 32; ++q) tp[q] = (h2){(_Float16)0.f, (_Float16)0.f};

    // fused u+v pass, one row at a time (no barrier inside the live range)
#pragma unroll
    for (int r = 0; r < 4; ++r) {
      const uint4* sr = (const uint4*)(Ep + (size_t)(4 * tid + r) * NM);
      h2 er[32];
#pragma unroll
      for (int j = 0; j < 8; ++j) {
        uint4 v = sr[j];
        er[j * 4 + 0] = __builtin_bit_cast(h2, v.x);
        er[j * 4 + 1] = __builtin_bit_cast(h2, v.y);
        er[j * 4 + 2] = __builtin_bit_cast(h2, v.z);
        er[j * 4 + 3] = __builtin_bit_cast(h2, v.w);
      }
      // u-dot: 4 ILP chains of 8
      float sa = 0.f, sb = 0.f, sc = 0.f, sd = 0.f;
#pragma unroll
      for (int q = 0; q < 8; ++q) {
        sa = fdot2f(er[q], evr[q], sa);
        sb = fdot2f(er[q + 8], evr[q + 8], sb);
        sc = fdot2f(er[q + 16], evr[q + 16], sc);
        sd = fdot2f(er[q + 24], evr[q + 24], sd);
      }
      const float eun =
          4.8828125e-4f * __builtin_amdgcn_rcpf(eu[r] * ((sa + sb) + (sc + sd)));
      eu[r] = eun;
      const float es = eun * EUSCALE;
      const h2 p = pkrtz(es, es);
#pragma unroll
      for (int q = 0; q < 32; ++q) tp[q] += er[q] * p;
    }

    // register-halving butterfly: after 5 steps lane l holds wave-partial for
    // col-pair q = bitrev5(l&31); lanes l and l^32 hold the two half-sums.
#pragma unroll
    for (int k = 0; k < 5; ++k) {
      const int nn = 32 >> k;
      const bool up = (lane >> k) & 1;
#pragma unroll
      for (int p = 0; p < (nn >> 1); ++p) {
        h2 keep = up ? tp[p + (nn >> 1)] : tp[p];
        h2 send = up ? tp[p] : tp[p + (nn >> 1)];
        int rv = __shfl_xor(__builtin_bit_cast(int, send), 1 << k, 64);
        tp[p] = keep + __builtin_bit_cast(h2, rv);
      }
    }
    pbuf[tid] = __builtin_bit_cast(unsigned int, tp[0]);
    __syncthreads();
    if (tid < 32) {
      const int j = tid;
      const int rev = ((j & 1) << 4) | ((j & 2) << 2) | (j & 4) | ((j & 8) >> 2) | ((j & 16) >> 4);
      float T0 = 0.f, T1 = 0.f;
#pragma unroll
      for (int wq = 0; wq < 8; ++wq) {
        h2 a = __builtin_bit_cast(h2, pbuf[wq * 64 + rev]);
        h2 c = __builtin_bit_cast(h2, pbuf[wq * 64 + rev + 32]);
        T0 += (float)a[0] + (float)c[0];
        T1 += (float)a[1] + (float)c[1];
      }
      const float e0 = evf[2 * j], e1 = evf[2 * j + 1];
      const float n0 = EUSCALE * __builtin_amdgcn_rcpf(e0 * T0);
      const float n1 = EUSCALE * __builtin_amdgcn_rcpf(e1 * T1);
      evf[2 * j] = n0;
      evf[2 * j + 1] = n1;
      evh[j] = pkrtz(n0, n1);
    }
    __syncthreads();
  }

  // epilogue: reload E once, P = E*eu*ev, Pt[b][m][h][n]; 8B packed stores.
  asm volatile("" ::: "memory");
  h2 ee[4][32];
#pragma unroll
  for (int r = 0; r < 4; ++r) {
    const uint4* sr = (const uint4*)(Ep + (size_t)(4 * tid + r) * NM);
#pragma unroll
    for (int j = 0; j < 8; ++j) {
      uint4 v = sr[j];
      ee[r][j * 4 + 0] = __builtin_bit_cast(h2, v.x);
      ee[r][j * 4 + 1] = __builtin_bit_cast(h2, v.y);
      ee[r][j * 4 + 2] = __builtin_bit_cast(h2, v.z);
      ee[r][j * 4 + 3] = __builtin_bit_cast(h2, v.w);
    }
  }
  _Float16* Pb = Pt + ((size_t)(b * 256 + h)) * NN;
#pragma unroll
  for (int q = 0; q < 32; ++q) {
    const float ev0 = evf[2 * q];
    const float ev1 = evf[2 * q + 1];
    float a0[4], a1[4];
#pragma unroll
    for (int r = 0; r < 4; ++r) {
      a0[r] = (float)ee[r][q][0] * eu[r] * ev0;   // row 4t+r, col 2q
      a1[r] = (float)ee[r][q][1] * eu[r] * ev1;   // row 4t+r, col 2q+1
    }
    uint2 st0, st1;
    st0.x = __builtin_bit_cast(unsigned int, pkrtz(a0[0], a0[1]));
    st0.y = __builtin_bit_cast(unsigned int, pkrtz(a0[2], a0[3]));
    st1.x = __builtin_bit_cast(unsigned int, pkrtz(a1[0], a1[1]));
    st1.y = __builtin_bit_cast(unsigned int, pkrtz(a1[2], a1[3]));
    *(uint2*)(Pb + (size_t)(2 * q) * 4 * NN + 4 * tid) = st0;
    *(uint2*)(Pb + (size_t)(2 * q + 1) * 4 * NN + 4 * tid) = st1;
  }
}

// ------------------------------------------------------------- k3: out GEMM
__global__ __launch_bounds__(512) void k3_out(const _Float16* __restrict__ Pt,
                                              const _Float16* __restrict__ xT,
                                              float* __restrict__ out) {
  __shared__ _Float16 As[128][72];
  __shared__ _Float16 Bs[64][72];
  const int b = blockIdx.z;
  const int hf = blockIdx.y;
  const int dt = blockIdx.x;
  const int tid = threadIdx.x;
  const int lane = tid & 63;
  const int wv = tid >> 6;
  const int lrow = lane & 15;
  const int kq = lane >> 4;

  f4 acc[4];
#pragma unroll
  for (int i = 0; i < 4; ++i) acc[i] = (f4){0.f, 0.f, 0.f, 0.f};

  const int ar = tid >> 2, ac = (tid & 3) * 16;
  const int brd = tid >> 3, bn = (tid & 7) * 8;
  const _Float16* asrc = Pt + ((size_t)(b * 256 + hf * 128 + ar) * NN + ac);
  const _Float16* bsrc = xT + ((size_t)(b * ND + dt * 64 + brd) * NN + bn);

  for (int kt = 0; kt < 32; ++kt) {
    const int k0 = kt * 64;
    h8 a0 = *(const h8*)(asrc + k0);
    h8 a1 = *(const h8*)(asrc + k0 + 8);
    h8 bv = *(const h8*)(bsrc + k0);
    *(h8*)&As[ar][ac] = a0;
    *(h8*)&As[ar][ac + 8] = a1;
    *(h8*)&Bs[brd][bn] = bv;
    __syncthreads();
#pragma unroll
    for (int s = 0; s < 2; ++s) {
      h8 af = *(const h8*)&As[wv * 16 + lrow][s * 32 + kq * 8];
#pragma unroll
      for (int cf = 0; cf < 4; ++cf) {
        h8 bf = *(const h8*)&Bs[cf * 16 + lrow][s * 32 + kq * 8];
        acc[cf] = __builtin_amdgcn_mfma_f32_16x16x32_f16(af, bf, acc[cf], 0, 0, 0);
      }
    }
    __syncthreads();
  }
#pragma unroll
  for (int cf = 0; cf < 4; ++cf) {
    const int d = dt * 64 + cf * 16 + lrow;
#pragma unroll
    for (int j = 0; j < 4; ++j) {
      const int row = hf * 128 + wv * 16 + kq * 4 + j;
      out[(size_t)(b * 256 + row) * ND + d] = acc[cf][j];
    }
  }
}

// ---------------------------------------------------------------- launcher
extern "C" void kernel_launch(void* const* d_in, const int* in_sizes, int n_in,
                              void* d_out, int out_size, void* d_ws, size_t ws_size,
                              hipStream_t stream) {
  const float* x = (const float*)d_in[0];
  const float* w = (const float*)d_in[1];
  float* out = (float*)d_out;
  char* ws = (char*)d_ws;
  _Float16* xT = (_Float16*)ws;
  _Float16* E  = (_Float16*)(ws + (size_t)33554432);
  _Float16* Pt = (_Float16*)(ws + (size_t)50331648);

  k0_xt<<<dim3(32, 8, NB), 256, 0, stream>>>(x, xT);
  k1_buildE<<<dim3(16, NB), 512, 0, stream>>>(x, w, E);
  k2_sinkhorn<<<dim3(64), 512, 0, stream>>>(E, Pt);
  k3_out<<<dim3(8, 2, NB), 512, 0, stream>>>(Pt, xT, out);
}

// Round 12
// 343.958 us; speedup vs baseline: 1.0176x; 1.0176x over previous
//
#include <hip/hip_runtime.h>
#include <hip/hip_fp16.h>

// OTK (optimal-transport kernel attention) for MI355X.
// Pipeline:
//   k0: xT[b][d][n] = fp16(x)            (transpose for k3 B-operand)
//   k1: E[b][h][n][m] = exp(-10*C*pf)    (fp16 MFMA GEMM + fused epilogue)
//   k2: exp-domain Sinkhorn, 256 thr/block x 8 rows/thr, fused single-read
//       row-streamed body with depth-2 load pipeline
//   k3: out[b][m*4+h][d] = Pt @ x        (fp16 MFMA GEMM)
// Identity: lse_m(K+u+v) = u + lse_m(K+v)  =>  plain Sinkhorn on E=exp(K).
//
// k2 saga conclusion (r1-r11): the RA's VGPR budget is tied to BLOCK SIZE:
// every 512-thread variant was capped at ~92 regs (remat/scratch no matter
// what: pins r4-r6, launch bounds r7, waves_per_eu r10/r11 — r11's SGPR
// 32->112 = scratch setup, not a raised budget). The 256-thread r1 kernel
// was granted the full 256 (VGPR_Count=256 measured). So: 256 threads,
// 8 rows/thread, FUSED u+v per row (E read once/iter = half of r3's L2
// traffic), triple-buffered row loads (load r+3 after compute r) so L2
// latency hides under ~2 rows of compute at 1 wave/SIMD. Peak pressure
// ~200 < 256 budget.

typedef _Float16 h2 __attribute__((ext_vector_type(2)));
typedef _Float16 h8 __attribute__((ext_vector_type(8)));
typedef float f4 __attribute__((ext_vector_type(4)));

#define NB 16
#define NN 2048
#define ND 512
#define NH 4
#define NM 64
#define NITER 30
#define EUSCALE 8.0f   // keeps fp16(eu*EUSCALE) in normal range (eu >= ~1e-5)

static __device__ __forceinline__ float fdot2f(h2 a, h2 b, float c) {
#if __has_builtin(__builtin_amdgcn_fdot2)
  return __builtin_amdgcn_fdot2(a, b, c, false);
#else
  return (float)a[0] * (float)b[0] + (float)a[1] * (float)b[1] + c;
#endif
}

static __device__ __forceinline__ h2 pkrtz(float a, float b) {
  return __builtin_bit_cast(h2, __builtin_amdgcn_cvt_pkrtz(a, b));
}

static __device__ __forceinline__ h8 pack8(float4 a, float4 b) {
  h8 r;
  r[0] = (_Float16)a.x; r[1] = (_Float16)a.y; r[2] = (_Float16)a.z; r[3] = (_Float16)a.w;
  r[4] = (_Float16)b.x; r[5] = (_Float16)b.y; r[6] = (_Float16)b.z; r[7] = (_Float16)b.w;
  return r;
}

static __device__ __forceinline__ float sq4(float4 a) {
  return a.x * a.x + a.y * a.y + a.z * a.z + a.w * a.w;
}

// ---------------------------------------------------------------- k0: x -> xT
__global__ __launch_bounds__(256) void k0_xt(const float* __restrict__ x,
                                             _Float16* __restrict__ xT) {
  __shared__ float tile[64][65];
  const int b = blockIdx.z;
  const int n0 = blockIdx.x * 64;
  const int d0 = blockIdx.y * 64;
  const int t = threadIdx.x;
  const int nr = t >> 2;
  const int ds = (t & 3) * 16;
  const float4* src = (const float4*)(x + ((size_t)(b * NN + n0 + nr) * ND + d0 + ds));
  float4 v0 = src[0], v1 = src[1], v2 = src[2], v3 = src[3];
  float vals[16] = {v0.x, v0.y, v0.z, v0.w, v1.x, v1.y, v1.z, v1.w,
                    v2.x, v2.y, v2.z, v2.w, v3.x, v3.y, v3.z, v3.w};
#pragma unroll
  for (int j = 0; j < 16; ++j) tile[ds + j][nr] = vals[j];
  __syncthreads();
  const int dr = t >> 2;
  const int ns = (t & 3) * 16;
  h8 o0, o1;
#pragma unroll
  for (int j = 0; j < 8; ++j) o0[j] = (_Float16)tile[dr][ns + j];
#pragma unroll
  for (int j = 0; j < 8; ++j) o1[j] = (_Float16)tile[dr][ns + 8 + j];
  _Float16* dst = xT + ((size_t)(b * ND + d0 + dr) * NN + n0 + ns);
  *(h8*)dst = o0;
  *(h8*)(dst + 8) = o1;
}

// ------------------------------------------------------------- k1: build E
__global__ __launch_bounds__(512) void k1_buildE(const float* __restrict__ x,
                                                 const float* __restrict__ w,
                                                 _Float16* __restrict__ E) {
  __shared__ _Float16 Ah[128][72];
  __shared__ _Float16 Bh[256][72];
  __shared__ float x2s[128][4];
  __shared__ float w2s[256][2];
  __shared__ float x2r[128];
  __shared__ float w2r[256];

  const int b = blockIdx.y;
  const int n0 = blockIdx.x * 128;
  const int tid = threadIdx.x;
  const int lane = tid & 63;
  const int wv = tid >> 6;
  const int lrow = lane & 15;
  const int kq = lane >> 4;

  f4 acc[16];
#pragma unroll
  for (int i = 0; i < 16; ++i) acc[i] = (f4){0.f, 0.f, 0.f, 0.f};

  const int ar = tid >> 2, ac = (tid & 3) * 16;
  const int br = tid >> 1, bc = (tid & 1) * 32;
  const float* xsrc = x + ((size_t)(b * NN + n0 + ar) * ND + ac);
  const float* wsrc = w + ((size_t)br * ND + bc);
  float x2p = 0.f, w2p = 0.f;

  for (int kt = 0; kt < 8; ++kt) {
    {
      const float4* s4 = (const float4*)(xsrc + kt * 64);
      float4 a0 = s4[0], a1 = s4[1], a2 = s4[2], a3 = s4[3];
      x2p += sq4(a0) + sq4(a1) + sq4(a2) + sq4(a3);
      *(h8*)&Ah[ar][ac] = pack8(a0, a1);
      *(h8*)&Ah[ar][ac + 8] = pack8(a2, a3);
    }
    {
      const float4* s4 = (const float4*)(wsrc + kt * 64);
      float4 u0 = s4[0], u1 = s4[1], u2 = s4[2], u3 = s4[3];
      float4 u4 = s4[4], u5 = s4[5], u6 = s4[6], u7 = s4[7];
      w2p += sq4(u0) + sq4(u1) + sq4(u2) + sq4(u3)
           + sq4(u4) + sq4(u5) + sq4(u6) + sq4(u7);
      *(h8*)&Bh[br][bc] = pack8(u0, u1);
      *(h8*)&Bh[br][bc + 8] = pack8(u2, u3);
      *(h8*)&Bh[br][bc + 16] = pack8(u4, u5);
      *(h8*)&Bh[br][bc + 24] = pack8(u6, u7);
    }
    __syncthreads();
#pragma unroll
    for (int s = 0; s < 2; ++s) {
      h8 af = *(const h8*)&Ah[wv * 16 + lrow][s * 32 + kq * 8];
#pragma unroll
      for (int cf = 0; cf < 16; ++cf) {
        h8 bf = *(const h8*)&Bh[cf * 16 + lrow][s * 32 + kq * 8];
        acc[cf] = __builtin_amdgcn_mfma_f32_16x16x32_f16(af, bf, acc[cf], 0, 0, 0);
      }
    }
    __syncthreads();
  }

  x2s[ar][tid & 3] = x2p;
  w2s[br][tid & 1] = w2p;
  __syncthreads();
  if (tid < 128) {
    x2r[tid] = x2s[tid][0] + x2s[tid][1] + x2s[tid][2] + x2s[tid][3];
  } else if (tid < 384) {
    const int r = tid - 128;
    w2r[r] = w2s[r][0] + w2s[r][1];
  }
  __syncthreads();

#pragma unroll
  for (int cf = 0; cf < 16; ++cf) {
    const int mg = cf * 16 + lrow;
    const int hh = mg >> 6;
    const int m = mg & 63;
    const float w2v = w2r[mg];
    const float bm = (float)m * (1.0f / 64.0f);
    _Float16* Eb = E + ((size_t)(b * NH + hh) * NN) * NM;
#pragma unroll
    for (int j = 0; j < 4; ++j) {
      const int nl = wv * 16 + kq * 4 + j;
      const int n = n0 + nl;
      const float c2 = x2r[nl] + w2v - 2.0f * acc[cf][j];
      const float Cd = sqrtf(fmaxf(c2, 0.0f));
      const float tt = (float)n * (1.0f / 2048.0f) - bm;
      const float pf = __expf(-100.0f * tt * tt);
      const float Ev = __expf(-10.0f * Cd * pf);
      Eb[(size_t)n * NM + m] = (_Float16)Ev;
    }
  }
}

// ------------------------------------------------------------ k2: Sinkhorn
// One block per (b,h). 256 threads x 8 rows (rows 8t..8t+7, contiguous 1KB
// per thread). Fused u+v per row, E read once/iter, triple-buffered loads.
#define H2C(v, c) __builtin_bit_cast(h2, (v).c)

#define LOADROW(P, rr) { \
  const uint4* sp_ = s0 + (rr) * 8; \
  P##0 = sp_[0]; P##1 = sp_[1]; P##2 = sp_[2]; P##3 = sp_[3]; \
  P##4 = sp_[4]; P##5 = sp_[5]; P##6 = sp_[6]; P##7 = sp_[7]; }

#define COMPROW(P, rr) { \
  h2 er_[32]; \
  er_[0]=H2C(P##0,x);  er_[1]=H2C(P##0,y);  er_[2]=H2C(P##0,z);  er_[3]=H2C(P##0,w); \
  er_[4]=H2C(P##1,x);  er_[5]=H2C(P##1,y);  er_[6]=H2C(P##1,z);  er_[7]=H2C(P##1,w); \
  er_[8]=H2C(P##2,x);  er_[9]=H2C(P##2,y);  er_[10]=H2C(P##2,z); er_[11]=H2C(P##2,w); \
  er_[12]=H2C(P##3,x); er_[13]=H2C(P##3,y); er_[14]=H2C(P##3,z); er_[15]=H2C(P##3,w); \
  er_[16]=H2C(P##4,x); er_[17]=H2C(P##4,y); er_[18]=H2C(P##4,z); er_[19]=H2C(P##4,w); \
  er_[20]=H2C(P##5,x); er_[21]=H2C(P##5,y); er_[22]=H2C(P##5,z); er_[23]=H2C(P##5,w); \
  er_[24]=H2C(P##6,x); er_[25]=H2C(P##6,y); er_[26]=H2C(P##6,z); er_[27]=H2C(P##6,w); \
  er_[28]=H2C(P##7,x); er_[29]=H2C(P##7,y); er_[30]=H2C(P##7,z); er_[31]=H2C(P##7,w); \
  float sa_ = 0.f, sb_ = 0.f, sc_ = 0.f, sd_ = 0.f; \
  _Pragma("unroll") \
  for (int q_ = 0; q_ < 8; ++q_) { \
    sa_ = fdot2f(er_[q_],      evr[q_],      sa_); \
    sb_ = fdot2f(er_[q_ + 8],  evr[q_ + 8],  sb_); \
    sc_ = fdot2f(er_[q_ + 16], evr[q_ + 16], sc_); \
    sd_ = fdot2f(er_[q_ + 24], evr[q_ + 24], sd_); } \
  const float eun_ = 4.8828125e-4f * \
      __builtin_amdgcn_rcpf(eu[rr] * ((sa_ + sb_) + (sc_ + sd_))); \
  eu[rr] = eun_; \
  const float es_ = eun_ * EUSCALE; \
  const h2 p_ = pkrtz(es_, es_); \
  _Pragma("unroll") \
  for (int q_ = 0; q_ < 32; ++q_) tp[q_] += er_[q_] * p_; }

__global__ __launch_bounds__(256, 1) void k2_sinkhorn(const _Float16* __restrict__ E,
                                                      _Float16* __restrict__ Pt) {
  const int bh = blockIdx.x;
  const int b = bh >> 2, h = bh & 3;
  const int tid = threadIdx.x;   // 0..255
  const int lane = tid & 63;

  __shared__ float evf[64];
  __shared__ __align__(16) h2 evh[32];
  __shared__ unsigned int pbuf[256];

  const _Float16* Ep = E + (size_t)bh * (NN * NM);
  const uint4* s0 = (const uint4*)(Ep + (size_t)(8 * tid) * NM);  // 8 rows = 64 uint4

  float eu[8] = {1.f, 1.f, 1.f, 1.f, 1.f, 1.f, 1.f, 1.f};
  if (tid < 64) evf[tid] = 1.f;
  if (tid < 32) evh[tid] = pkrtz(1.f, 1.f);
  __syncthreads();

#pragma unroll 1
  for (int it = 0; it < NITER; ++it) {
    asm volatile("" ::: "memory");   // keep E loads inside the loop
    // ev broadcast from LDS (packed fp16)
    h2 evr[32];
    {
      const uint4* ev4 = (const uint4*)evh;
#pragma unroll
      for (int j = 0; j < 8; ++j) {
        uint4 v = ev4[j];
        evr[j * 4 + 0] = __builtin_bit_cast(h2, v.x);
        evr[j * 4 + 1] = __builtin_bit_cast(h2, v.y);
        evr[j * 4 + 2] = __builtin_bit_cast(h2, v.z);
        evr[j * 4 + 3] = __builtin_bit_cast(h2, v.w);
      }
    }
    h2 tp[32];
#pragma unroll
    for (int q = 0; q < 32; ++q) tp[q] = (h2){(_Float16)0.f, (_Float16)0.f};

    // depth-2 pipelined fused u+v pass over 8 rows (triple buffer A/B/C)
    uint4 A0, A1, A2, A3, A4, A5, A6, A7;
    uint4 B0, B1, B2, B3, B4, B5, B6, B7;
    uint4 C0, C1, C2, C3, C4, C5, C6, C7;
    LOADROW(A, 0)
    LOADROW(B, 1)
    LOADROW(C, 2)
    COMPROW(A, 0) LOADROW(A, 3)
    COMPROW(B, 1) LOADROW(B, 4)
    COMPROW(C, 2) LOADROW(C, 5)
    COMPROW(A, 3) LOADROW(A, 6)
    COMPROW(B, 4) LOADROW(B, 7)
    COMPROW(C, 5)
    COMPROW(A, 6)
    COMPROW(B, 7)

    // register-halving butterfly: after 5 steps lane l holds wave-partial for
    // col-pair q = bitrev5(l&31); lanes l and l^32 hold the two half-sums.
#pragma unroll
    for (int k = 0; k < 5; ++k) {
      const int nn = 32 >> k;
      const bool up = (lane >> k) & 1;
#pragma unroll
      for (int p = 0; p < (nn >> 1); ++p) {
        h2 keep = up ? tp[p + (nn >> 1)] : tp[p];
        h2 send = up ? tp[p] : tp[p + (nn >> 1)];
        int rv = __shfl_xor(__builtin_bit_cast(int, send), 1 << k, 64);
        tp[p] = keep + __builtin_bit_cast(h2, rv);
      }
    }
    pbuf[tid] = __builtin_bit_cast(unsigned int, tp[0]);
    __syncthreads();
    if (tid < 32) {
      const int j = tid;
      const int rev = ((j & 1) << 4) | ((j & 2) << 2) | (j & 4) | ((j & 8) >> 2) | ((j & 16) >> 4);
      float T0 = 0.f, T1 = 0.f;
#pragma unroll
      for (int wq = 0; wq < 4; ++wq) {
        h2 a = __builtin_bit_cast(h2, pbuf[wq * 64 + rev]);
        h2 c = __builtin_bit_cast(h2, pbuf[wq * 64 + rev + 32]);
        T0 += (float)a[0] + (float)c[0];
        T1 += (float)a[1] + (float)c[1];
      }
      const float e0 = evf[2 * j], e1 = evf[2 * j + 1];
      const float n0 = EUSCALE * __builtin_amdgcn_rcpf(e0 * T0);
      const float n1 = EUSCALE * __builtin_amdgcn_rcpf(e1 * T1);
      evf[2 * j] = n0;
      evf[2 * j + 1] = n1;
      evh[j] = pkrtz(n0, n1);
    }
    __syncthreads();
  }

  // epilogue: reload E (two 4-row halves), P = E*eu*ev, Pt[b][m][h][n];
  // rows 8t+4H..8t+4H+3 pack into one 8B store per col.
  asm volatile("" ::: "memory");
  _Float16* Pb = Pt + ((size_t)(b * 256 + h)) * NN;
#pragma unroll
  for (int half = 0; half < 2; ++half) {
    h2 ee[4][32];
#pragma unroll
    for (int r = 0; r < 4; ++r) {
      const uint4* sr = s0 + (4 * half + r) * 8;
#pragma unroll
      for (int j = 0; j < 8; ++j) {
        uint4 v = sr[j];
        ee[r][j * 4 + 0] = __builtin_bit_cast(h2, v.x);
        ee[r][j * 4 + 1] = __builtin_bit_cast(h2, v.y);
        ee[r][j * 4 + 2] = __builtin_bit_cast(h2, v.z);
        ee[r][j * 4 + 3] = __builtin_bit_cast(h2, v.w);
      }
    }
#pragma unroll
    for (int q = 0; q < 32; ++q) {
      const float ev0 = evf[2 * q];
      const float ev1 = evf[2 * q + 1];
      float a0[4], a1[4];
#pragma unroll
      for (int r = 0; r < 4; ++r) {
        a0[r] = (float)ee[r][q][0] * eu[4 * half + r] * ev0;   // col 2q
        a1[r] = (float)ee[r][q][1] * eu[4 * half + r] * ev1;   // col 2q+1
      }
      uint2 st0, st1;
      st0.x = __builtin_bit_cast(unsigned int, pkrtz(a0[0], a0[1]));
      st0.y = __builtin_bit_cast(unsigned int, pkrtz(a0[2], a0[3]));
      st1.x = __builtin_bit_cast(unsigned int, pkrtz(a1[0], a1[1]));
      st1.y = __builtin_bit_cast(unsigned int, pkrtz(a1[2], a1[3]));
      *(uint2*)(Pb + (size_t)(2 * q) * 4 * NN + 8 * tid + 4 * half) = st0;
      *(uint2*)(Pb + (size_t)(2 * q + 1) * 4 * NN + 8 * tid + 4 * half) = st1;
    }
  }
}

// ------------------------------------------------------------- k3: out GEMM
__global__ __launch_bounds__(512) void k3_out(const _Float16* __restrict__ Pt,
                                              const _Float16* __restrict__ xT,
                                              float* __restrict__ out) {
  __shared__ _Float16 As[128][72];
  __shared__ _Float16 Bs[64][72];
  const int b = blockIdx.z;
  const int hf = blockIdx.y;
  const int dt = blockIdx.x;
  const int tid = threadIdx.x;
  const int lane = tid & 63;
  const int wv = tid >> 6;
  const int lrow = lane & 15;
  const int kq = lane >> 4;

  f4 acc[4];
#pragma unroll
  for (int i = 0; i < 4; ++i) acc[i] = (f4){0.f, 0.f, 0.f, 0.f};

  const int ar = tid >> 2, ac = (tid & 3) * 16;
  const int brd = tid >> 3, bn = (tid & 7) * 8;
  const _Float16* asrc = Pt + ((size_t)(b * 256 + hf * 128 + ar) * NN + ac);
  const _Float16* bsrc = xT + ((size_t)(b * ND + dt * 64 + brd) * NN + bn);

  for (int kt = 0; kt < 32; ++kt) {
    const int k0 = kt * 64;
    h8 a0 = *(const h8*)(asrc + k0);
    h8 a1 = *(const h8*)(asrc + k0 + 8);
    h8 bv = *(const h8*)(bsrc + k0);
    *(h8*)&As[ar][ac] = a0;
    *(h8*)&As[ar][ac + 8] = a1;
    *(h8*)&Bs[brd][bn] = bv;
    __syncthreads();
#pragma unroll
    for (int s = 0; s < 2; ++s) {
      h8 af = *(const h8*)&As[wv * 16 + lrow][s * 32 + kq * 8];
#pragma unroll
      for (int cf = 0; cf < 4; ++cf) {
        h8 bf = *(const h8*)&Bs[cf * 16 + lrow][s * 32 + kq * 8];
        acc[cf] = __builtin_amdgcn_mfma_f32_16x16x32_f16(af, bf, acc[cf], 0, 0, 0);
      }
    }
    __syncthreads();
  }
#pragma unroll
  for (int cf = 0; cf < 4; ++cf) {
    const int d = dt * 64 + cf * 16 + lrow;
#pragma unroll
    for (int j = 0; j < 4; ++j) {
      const int row = hf * 128 + wv * 16 + kq * 4 + j;
      out[(size_t)(b * 256 + row) * ND + d] = acc[cf][j];
    }
  }
}

// ---------------------------------------------------------------- launcher
extern "C" void kernel_launch(void* const* d_in, const int* in_sizes, int n_in,
                              void* d_out, int out_size, void* d_ws, size_t ws_size,
                              hipStream_t stream) {
  const float* x = (const float*)d_in[0];
  const float* w = (const float*)d_in[1];
  float* out = (float*)d_out;
  char* ws = (char*)d_ws;
  _Float16* xT = (_Float16*)ws;
  _Float16* E  = (_Float16*)(ws + (size_t)33554432);
  _Float16* Pt = (_Float16*)(ws + (size_t)50331648);

  k0_xt<<<dim3(32, 8, NB), 256, 0, stream>>>(x, xT);
  k1_buildE<<<dim3(16, NB), 512, 0, stream>>>(x, w, E);
  k2_sinkhorn<<<dim3(64), 256, 0, stream>>>(E, Pt);
  k3_out<<<dim3(8, 2, NB), 512, 0, stream>>>(Pt, xT, out);
}

// Round 13
// 161.840 us; speedup vs baseline: 2.1627x; 2.1253x over previous
//
#include <hip/hip_runtime.h>
#include <hip/hip_fp16.h>

// OTK (optimal-transport kernel attention) for MI355X.
// Pipeline:
//   k01: fused role-split kernel — k0-role blocks transpose x -> xT fp16,
//        k1-role blocks build E = exp(-10*C*pf) via fp16 MFMA. Independent
//        work overlaps across CUs instead of serializing on the stream.
//   k2:  exp-domain Sinkhorn (r10 structure, measured 80.3 us — best of 12
//        rounds; remat-streaming at the per-CU L2 roof).
//   k3:  out = Pt @ xT, 256-thr blocks (2/CU) + register prefetch.
// Identity: lse_m(K+u+v) = u + lse_m(K+v)  =>  plain Sinkhorn on E=exp(K).
//
// k2 saga (r1-r12, closed): RA refuses large loop-carried live ranges at
// >256-thread blocks (~92-reg cap; pins spill, waves_per_eu ignored for
// budget) and fused single-read bodies serialize loads (VALUBusy 4%).
// r1 proved 256-thr CAN get 256 VGPRs but is then 1-wave/SIMD latency-bound.
// The remat double-read streaming structure (r3/r10) at 80 us is the
// practical floor; this round banks it and optimizes k0/k1/k3 instead.

typedef _Float16 h2 __attribute__((ext_vector_type(2)));
typedef _Float16 h8 __attribute__((ext_vector_type(8)));
typedef float f4 __attribute__((ext_vector_type(4)));

#define NB 16
#define NN 2048
#define ND 512
#define NH 4
#define NM 64
#define NITER 30
#define EUSCALE 8.0f   // keeps fp16(eu*EUSCALE) in normal range (eu >= ~1e-5)

static __device__ __forceinline__ float fdot2f(h2 a, h2 b, float c) {
#if __has_builtin(__builtin_amdgcn_fdot2)
  return __builtin_amdgcn_fdot2(a, b, c, false);
#else
  return (float)a[0] * (float)b[0] + (float)a[1] * (float)b[1] + c;
#endif
}

static __device__ __forceinline__ h2 pkrtz(float a, float b) {
  return __builtin_bit_cast(h2, __builtin_amdgcn_cvt_pkrtz(a, b));
}

static __device__ __forceinline__ h8 pack8(float4 a, float4 b) {
  h8 r;
  r[0] = (_Float16)a.x; r[1] = (_Float16)a.y; r[2] = (_Float16)a.z; r[3] = (_Float16)a.w;
  r[4] = (_Float16)b.x; r[5] = (_Float16)b.y; r[6] = (_Float16)b.z; r[7] = (_Float16)b.w;
  return r;
}

static __device__ __forceinline__ float sq4(float4 a) {
  return a.x * a.x + a.y * a.y + a.z * a.z + a.w * a.w;
}

// -------------------------------------------------- k01: fused k0 | k1
// grid = 2048 (k0-role) + 256 (k1-role) blocks x 512 threads.
// Dynamic LDS (60928 B) re-used per role:
//   k0-role: float tile[128][65]            (33280 B; two 64x64 tiles)
//   k1-role: Ah[128][72] fp16   @ 0        (18432)
//            Bh[256][72] fp16   @ 18432    (36864)
//            x2s[128][4] f32    @ 55296    ( 2048)
//            w2s[256][2] f32    @ 57344    ( 2048)
//            x2r[128]    f32    @ 59392    (  512)
//            w2r[256]    f32    @ 59904    ( 1024)  -> total 60928
__global__ __launch_bounds__(512) void k01_fused(const float* __restrict__ x,
                                                 const float* __restrict__ w,
                                                 _Float16* __restrict__ xT,
                                                 _Float16* __restrict__ E) {
  extern __shared__ __align__(16) char smem[];
  const int bid = blockIdx.x;
  const int tid = threadIdx.x;

  if (bid < 2048) {
    // ---------------- k0 role: transpose two 64x64 tiles ----------------
    auto tile = (float(*)[65])smem;          // [128][65]
    const int sub = tid >> 8;                // 0/1: which tile
    const int t = tid & 255;
    const int xt = bid & 15;                 // pair index
    const int dt = (bid >> 4) & 7;
    const int b = bid >> 7;
    const int n0 = (xt * 2 + sub) * 64;
    const int d0 = dt * 64;
    const int rbase = sub << 6;

    const int nr = t >> 2;
    const int ds = (t & 3) * 16;
    const float4* src = (const float4*)(x + ((size_t)(b * NN + n0 + nr) * ND + d0 + ds));
    float4 v0 = src[0], v1 = src[1], v2 = src[2], v3 = src[3];
    float vals[16] = {v0.x, v0.y, v0.z, v0.w, v1.x, v1.y, v1.z, v1.w,
                      v2.x, v2.y, v2.z, v2.w, v3.x, v3.y, v3.z, v3.w};
#pragma unroll
    for (int j = 0; j < 16; ++j) tile[rbase + ds + j][nr] = vals[j];
    __syncthreads();
    const int dr = t >> 2;
    const int ns = (t & 3) * 16;
    h8 o0, o1;
#pragma unroll
    for (int j = 0; j < 8; ++j) o0[j] = (_Float16)tile[rbase + dr][ns + j];
#pragma unroll
    for (int j = 0; j < 8; ++j) o1[j] = (_Float16)tile[rbase + dr][ns + 8 + j];
    _Float16* dst = xT + ((size_t)(b * ND + d0 + dr) * NN + n0 + ns);
    *(h8*)dst = o0;
    *(h8*)(dst + 8) = o1;
    return;
  }

  // ------------------- k1 role: build E (fp16 MFMA) --------------------
  auto Ah  = (_Float16(*)[72])(smem);
  auto Bh  = (_Float16(*)[72])(smem + 18432);
  auto x2s = (float(*)[4])(smem + 55296);
  auto w2s = (float(*)[2])(smem + 57344);
  float* x2r = (float*)(smem + 59392);
  float* w2r = (float*)(smem + 59904);

  const int bid2 = bid - 2048;
  const int b = bid2 >> 4;
  const int n0 = (bid2 & 15) * 128;
  const int lane = tid & 63;
  const int wv = tid >> 6;
  const int lrow = lane & 15;
  const int kq = lane >> 4;

  f4 acc[16];
#pragma unroll
  for (int i = 0; i < 16; ++i) acc[i] = (f4){0.f, 0.f, 0.f, 0.f};

  const int ar = tid >> 2, ac = (tid & 3) * 16;
  const int br = tid >> 1, bc = (tid & 1) * 32;
  const float* xsrc = x + ((size_t)(b * NN + n0 + ar) * ND + ac);
  const float* wsrc = w + ((size_t)br * ND + bc);
  float x2p = 0.f, w2p = 0.f;

  for (int kt = 0; kt < 8; ++kt) {
    {
      const float4* s4 = (const float4*)(xsrc + kt * 64);
      float4 a0 = s4[0], a1 = s4[1], a2 = s4[2], a3 = s4[3];
      x2p += sq4(a0) + sq4(a1) + sq4(a2) + sq4(a3);
      *(h8*)&Ah[ar][ac] = pack8(a0, a1);
      *(h8*)&Ah[ar][ac + 8] = pack8(a2, a3);
    }
    {
      const float4* s4 = (const float4*)(wsrc + kt * 64);
      float4 u0 = s4[0], u1 = s4[1], u2 = s4[2], u3 = s4[3];
      float4 u4 = s4[4], u5 = s4[5], u6 = s4[6], u7 = s4[7];
      w2p += sq4(u0) + sq4(u1) + sq4(u2) + sq4(u3)
           + sq4(u4) + sq4(u5) + sq4(u6) + sq4(u7);
      *(h8*)&Bh[br][bc] = pack8(u0, u1);
      *(h8*)&Bh[br][bc + 8] = pack8(u2, u3);
      *(h8*)&Bh[br][bc + 16] = pack8(u4, u5);
      *(h8*)&Bh[br][bc + 24] = pack8(u6, u7);
    }
    __syncthreads();
#pragma unroll
    for (int s = 0; s < 2; ++s) {
      h8 af = *(const h8*)&Ah[wv * 16 + lrow][s * 32 + kq * 8];
#pragma unroll
      for (int cf = 0; cf < 16; ++cf) {
        h8 bf = *(const h8*)&Bh[cf * 16 + lrow][s * 32 + kq * 8];
        acc[cf] = __builtin_amdgcn_mfma_f32_16x16x32_f16(af, bf, acc[cf], 0, 0, 0);
      }
    }
    __syncthreads();
  }

  x2s[ar][tid & 3] = x2p;
  w2s[br][tid & 1] = w2p;
  __syncthreads();
  if (tid < 128) {
    x2r[tid] = x2s[tid][0] + x2s[tid][1] + x2s[tid][2] + x2s[tid][3];
  } else if (tid < 384) {
    const int r = tid - 128;
    w2r[r] = w2s[r][0] + w2s[r][1];
  }
  __syncthreads();

#pragma unroll
  for (int cf = 0; cf < 16; ++cf) {
    const int mg = cf * 16 + lrow;
    const int hh = mg >> 6;
    const int m = mg & 63;
    const float w2v = w2r[mg];
    const float bm = (float)m * (1.0f / 64.0f);
    _Float16* Eb = E + ((size_t)(b * NH + hh) * NN) * NM;
#pragma unroll
    for (int j = 0; j < 4; ++j) {
      const int nl = wv * 16 + kq * 4 + j;
      const int n = n0 + nl;
      const float c2 = x2r[nl] + w2v - 2.0f * acc[cf][j];
      const float Cd = sqrtf(fmaxf(c2, 0.0f));
      const float tt = (float)n * (1.0f / 2048.0f) - bm;
      const float pf = __expf(-100.0f * tt * tt);
      const float Ev = __expf(-10.0f * Cd * pf);
      Eb[(size_t)n * NM + m] = (_Float16)Ev;
    }
  }
}

// ------------------------------------------------------------ k2: Sinkhorn
// One block per (b,h). 512 threads x 4 adjacent rows; r10 structure
// (measured 80.3 us): clean arrays, compiler remat streaming from L2.
__global__ __launch_bounds__(512)
__attribute__((amdgpu_waves_per_eu(2, 2)))
void k2_sinkhorn(const _Float16* __restrict__ E,
                 _Float16* __restrict__ Pt) {
  const int bh = blockIdx.x;
  const int b = bh >> 2, h = bh & 3;
  const int tid = threadIdx.x;
  const int lane = tid & 63;

  __shared__ float evf[64];
  __shared__ __align__(16) h2 evh[32];
  __shared__ unsigned int pbuf[512];

  const _Float16* Ep = E + (size_t)bh * (NN * NM);

  // rows 4*tid .. 4*tid+3 (adjacent: packs the Pt epilogue into 8B stores)
  h2 e[4][32];
#pragma unroll
  for (int i = 0; i < 4; ++i) {
    const uint4* src = (const uint4*)(Ep + (size_t)(4 * tid + i) * NM);
#pragma unroll
    for (int q = 0; q < 8; ++q) {
      uint4 v = src[q];
      e[i][q * 4 + 0] = __builtin_bit_cast(h2, v.x);
      e[i][q * 4 + 1] = __builtin_bit_cast(h2, v.y);
      e[i][q * 4 + 2] = __builtin_bit_cast(h2, v.z);
      e[i][q * 4 + 3] = __builtin_bit_cast(h2, v.w);
    }
  }

  float eu[4] = {1.f, 1.f, 1.f, 1.f};
  if (tid < 64) evf[tid] = 1.f;
  if (tid < 32) evh[tid] = pkrtz(1.f, 1.f);
  __syncthreads();

#pragma unroll 1
  for (int it = 0; it < NITER; ++it) {
    // broadcast ev (fp16-packed master in LDS)
    h2 evr[32];
    {
      const uint4* ev4 = (const uint4*)evh;
#pragma unroll
      for (int q8 = 0; q8 < 8; ++q8) {
        uint4 v = ev4[q8];
        evr[q8 * 4 + 0] = __builtin_bit_cast(h2, v.x);
        evr[q8 * 4 + 1] = __builtin_bit_cast(h2, v.y);
        evr[q8 * 4 + 2] = __builtin_bit_cast(h2, v.z);
        evr[q8 * 4 + 3] = __builtin_bit_cast(h2, v.w);
      }
    }
    // u-pass: S[n] = sum_m E*ev ; eu = (1/N)/(eu*S).  8 chains for ILP.
    float sa[4] = {0.f, 0.f, 0.f, 0.f};
    float sb[4] = {0.f, 0.f, 0.f, 0.f};
#pragma unroll
    for (int q = 0; q < 16; ++q) {
#pragma unroll
      for (int i = 0; i < 4; ++i) sa[i] = fdot2f(e[i][q], evr[q], sa[i]);
    }
#pragma unroll
    for (int q = 16; q < 32; ++q) {
#pragma unroll
      for (int i = 0; i < 4; ++i) sb[i] = fdot2f(e[i][q], evr[q], sb[i]);
    }
#pragma unroll
    for (int i = 0; i < 4; ++i) {
      eu[i] = 4.8828125e-4f * __builtin_amdgcn_rcpf(eu[i] * (sa[i] + sb[i]));
    }
    // v-pass local: T'[m] = sum_rows E * (eu*EUSCALE)
    h2 eup[4];
#pragma unroll
    for (int i = 0; i < 4; ++i) {
      const float es = eu[i] * EUSCALE;
      eup[i] = pkrtz(es, es);
    }
    h2 tp[32];
#pragma unroll
    for (int q = 0; q < 32; ++q) {
      tp[q] = e[0][q] * eup[0] + e[1][q] * eup[1];
      tp[q] += e[2][q] * eup[2] + e[3][q] * eup[3];
    }
    // register-halving butterfly: after 5 steps lane l holds wave-partial for
    // col-pair q = bitrev5(l&31); lanes l and l^32 hold the two half-sums.
#pragma unroll
    for (int k = 0; k < 5; ++k) {
      const int nn = 32 >> k;
      const bool up = (lane >> k) & 1;
#pragma unroll
      for (int p = 0; p < (nn >> 1); ++p) {
        h2 keep = up ? tp[p + (nn >> 1)] : tp[p];
        h2 send = up ? tp[p] : tp[p + (nn >> 1)];
        int rv = __shfl_xor(__builtin_bit_cast(int, send), 1 << k, 64);
        tp[p] = keep + __builtin_bit_cast(h2, rv);
      }
    }
    pbuf[tid] = __builtin_bit_cast(unsigned int, tp[0]);
    __syncthreads();
    if (tid < 32) {
      const int j = tid;
      const int rev = ((j & 1) << 4) | ((j & 2) << 2) | (j & 4) | ((j & 8) >> 2) | ((j & 16) >> 4);
      float T0 = 0.f, T1 = 0.f;
#pragma unroll
      for (int wq = 0; wq < 8; ++wq) {
        h2 a = __builtin_bit_cast(h2, pbuf[wq * 64 + rev]);
        h2 c = __builtin_bit_cast(h2, pbuf[wq * 64 + rev + 32]);
        T0 += (float)a[0] + (float)c[0];
        T1 += (float)a[1] + (float)c[1];
      }
      const float e0 = evf[2 * j], e1 = evf[2 * j + 1];
      // ev_new = 1/(ev_old*T) with T = T'/EUSCALE
      const float n0 = EUSCALE * __builtin_amdgcn_rcpf(e0 * T0);
      const float n1 = EUSCALE * __builtin_amdgcn_rcpf(e1 * T1);
      evf[2 * j] = n0;
      evf[2 * j + 1] = n1;
      evh[j] = pkrtz(n0, n1);
    }
    __syncthreads();
  }

  // epilogue: P = E*eu*ev, Pt[b][m][h][n] fp16; rows 4t..4t+3 -> 8B stores.
  _Float16* Pb = Pt + ((size_t)(b * 256 + h)) * NN;
#pragma unroll
  for (int q = 0; q < 32; ++q) {
    const float ev0 = evf[2 * q];
    const float ev1 = evf[2 * q + 1];
    float a0[4], a1[4];
#pragma unroll
    for (int i = 0; i < 4; ++i) {
      a0[i] = (float)e[i][q][0] * eu[i] * ev0;   // row 4t+i, col 2q
      a1[i] = (float)e[i][q][1] * eu[i] * ev1;   // row 4t+i, col 2q+1
    }
    uint2 st0, st1;
    st0.x = __builtin_bit_cast(unsigned int, pkrtz(a0[0], a0[1]));
    st0.y = __builtin_bit_cast(unsigned int, pkrtz(a0[2], a0[3]));
    st1.x = __builtin_bit_cast(unsigned int, pkrtz(a1[0], a1[1]));
    st1.y = __builtin_bit_cast(unsigned int, pkrtz(a1[2], a1[3]));
    *(uint2*)(Pb + (size_t)(2 * q) * 4 * NN + 4 * tid) = st0;
    *(uint2*)(Pb + (size_t)(2 * q + 1) * 4 * NN + 4 * tid) = st1;
  }
}

// ------------------------------------------------------------- k3: out GEMM
// 256 threads, 64x64 output tile, grid (8,4,16)=512 blocks (2/CU), with
// register prefetch of the next K-tile issued right after the first barrier
// so global-load latency hides under the MFMA cluster.
__global__ __launch_bounds__(256) void k3_out(const _Float16* __restrict__ Pt,
                                              const _Float16* __restrict__ xT,
                                              float* __restrict__ out) {
  __shared__ _Float16 As[64][72];
  __shared__ _Float16 Bs[64][72];
  const int b = blockIdx.z;
  const int hf = blockIdx.y;   // 0..3: 64-row slab of the 256 output rows
  const int dt = blockIdx.x;   // 0..7: 64-col slab of d
  const int tid = threadIdx.x;
  const int lane = tid & 63;
  const int wv = tid >> 6;     // 0..3
  const int lrow = lane & 15;
  const int kq = lane >> 4;

  f4 acc[4];
#pragma unroll
  for (int i = 0; i < 4; ++i) acc[i] = (f4){0.f, 0.f, 0.f, 0.f};

  const int ar = tid >> 2, ac = (tid & 3) * 16;
  const _Float16* asrc = Pt + ((size_t)(b * 256 + hf * 64 + ar) * NN + ac);
  const _Float16* bsrc = xT + ((size_t)(b * ND + dt * 64 + ar) * NN + ac);

  h8 a0 = *(const h8*)(asrc);
  h8 a1 = *(const h8*)(asrc + 8);
  h8 b0 = *(const h8*)(bsrc);
  h8 b1 = *(const h8*)(bsrc + 8);

  for (int kt = 0; kt < 32; ++kt) {
    *(h8*)&As[ar][ac] = a0;
    *(h8*)&As[ar][ac + 8] = a1;
    *(h8*)&Bs[ar][ac] = b0;
    *(h8*)&Bs[ar][ac + 8] = b1;
    __syncthreads();
    if (kt < 31) {
      const int k0 = (kt + 1) * 64;
      a0 = *(const h8*)(asrc + k0);
      a1 = *(const h8*)(asrc + k0 + 8);
      b0 = *(const h8*)(bsrc + k0);
      b1 = *(const h8*)(bsrc + k0 + 8);
    }
#pragma unroll
    for (int s = 0; s < 2; ++s) {
      h8 af = *(const h8*)&As[wv * 16 + lrow][s * 32 + kq * 8];
#pragma unroll
      for (int cf = 0; cf < 4; ++cf) {
        h8 bf = *(const h8*)&Bs[cf * 16 + lrow][s * 32 + kq * 8];
        acc[cf] = __builtin_amdgcn_mfma_f32_16x16x32_f16(af, bf, acc[cf], 0, 0, 0);
      }
    }
    __syncthreads();
  }
#pragma unroll
  for (int cf = 0; cf < 4; ++cf) {
    const int d = dt * 64 + cf * 16 + lrow;
#pragma unroll
    for (int j = 0; j < 4; ++j) {
      const int row = hf * 64 + wv * 16 + kq * 4 + j;
      out[(size_t)(b * 256 + row) * ND + d] = acc[cf][j];
    }
  }
}

// ---------------------------------------------------------------- launcher
extern "C" void kernel_launch(void* const* d_in, const int* in_sizes, int n_in,
                              void* d_out, int out_size, void* d_ws, size_t ws_size,
                              hipStream_t stream) {
  const float* x = (const float*)d_in[0];
  const float* w = (const float*)d_in[1];
  float* out = (float*)d_out;
  char* ws = (char*)d_ws;
  // ws layout:
  //   xT : 16*512*2048 fp16 = 33,554,432 B
  //   E  : 16*4*2048*64 fp16 = 16,777,216 B
  //   Pt : 16*64*4*2048 fp16 = 16,777,216 B
  _Float16* xT = (_Float16*)ws;
  _Float16* E  = (_Float16*)(ws + (size_t)33554432);
  _Float16* Pt = (_Float16*)(ws + (size_t)50331648);

  k01_fused<<<2304, 512, 60928, stream>>>(x, w, xT, E);
  k2_sinkhorn<<<64, 512, 0, stream>>>(E, Pt);
  k3_out<<<dim3(8, 4, NB), 256, 0, stream>>>(Pt, xT, out);
}